// Round 1
// baseline (346.455 us; speedup 1.0000x reference)
//
#include <hip/hip_runtime.h>

typedef short bf16x8 __attribute__((ext_vector_type(8)));
typedef float f32x4 __attribute__((ext_vector_type(4)));

#define LOG2E 1.44269504088896340736f
#define INV_SCALE 0.03608439182435161f /* 1/sqrt(768) */

__device__ __forceinline__ unsigned short f2bf(float f) {
  unsigned u = __float_as_uint(f);
  u += 0x7fffu + ((u >> 16) & 1u);   // round-to-nearest-even
  return (unsigned short)(u >> 16);
}

__device__ __forceinline__ void gload_lds16(const void* g, void* l) {
  __builtin_amdgcn_global_load_lds(
      (const __attribute__((address_space(1))) void*)g,
      (__attribute__((address_space(3))) void*)l, 16, 0, 0);
}

__global__ __launch_bounds__(256) void f2bf_kernel(const float* __restrict__ src,
                                                   unsigned short* __restrict__ dst,
                                                   int n4) {
  int i = blockIdx.x * blockDim.x + threadIdx.x;
  if (i < n4) {
    float4 v = ((const float4*)src)[i];
    ushort4 o;
    o.x = f2bf(v.x); o.y = f2bf(v.y); o.z = f2bf(v.z); o.w = f2bf(v.w);
    ((ushort4*)dst)[i] = o;
  }
}

// C = A[M][K] * B[N][K]^T, bf16 in, fp32 acc. 128x128 tile, BK=32, 4 waves (2x2 of 64x64).
// EPI=0: QKV epilogue (bias, scale Q, scatter to Q/K/VT).  EPI=1: proj epilogue (bias, fp32 out).
template<int EPI>
__global__ __launch_bounds__(256) void gemm_bt(
    const unsigned short* __restrict__ A,
    const unsigned short* __restrict__ B,
    const float* __restrict__ bias,
    void* __restrict__ out0,
    unsigned short* __restrict__ Kb,
    unsigned short* __restrict__ VTb) {
  constexpr int K = 768;
  __shared__ unsigned short Alds[128 * 32];
  __shared__ unsigned short Blds[128 * 32];
  const int tid = threadIdx.x;
  const int w = tid >> 6, lane = tid & 63;
  const int g = lane >> 4, qq = lane & 15;
  const int wr = w >> 1, wc = w & 1;
  const int mbase = blockIdx.y * 128;
  const int nbase = blockIdx.x * 128;
  const unsigned short* Ab = A + (size_t)mbase * K;
  const unsigned short* Bb = B + (size_t)nbase * K;

  f32x4 acc[4][4];
#pragma unroll
  for (int i = 0; i < 4; i++)
#pragma unroll
    for (int j = 0; j < 4; j++) acc[i][j] = (f32x4){0.f, 0.f, 0.f, 0.f};

  const int idx0 = (w * 2) * 64 + lane;      // 0..511 chunk ids (16B each)
  const int idx1 = (w * 2 + 1) * 64 + lane;
  const int r0 = idx0 >> 2, c0 = idx0 & 3;   // 4 chunks per 64B row-slice
  const int r1 = idx1 >> 2, c1 = idx1 & 3;

  for (int k0 = 0; k0 < K; k0 += 32) {
    __syncthreads();
    gload_lds16(Ab + (size_t)r0 * K + k0 + c0 * 8, &Alds[idx0 * 8]);
    gload_lds16(Ab + (size_t)r1 * K + k0 + c1 * 8, &Alds[idx1 * 8]);
    gload_lds16(Bb + (size_t)r0 * K + k0 + c0 * 8, &Blds[idx0 * 8]);
    gload_lds16(Bb + (size_t)r1 * K + k0 + c1 * 8, &Blds[idx1 * 8]);
    __syncthreads();
    bf16x8 af[4], bfr[4];
#pragma unroll
    for (int mi = 0; mi < 4; mi++)
      af[mi] = *(const bf16x8*)&Alds[(wr * 64 + mi * 16 + qq) * 32 + g * 8];
#pragma unroll
    for (int ni = 0; ni < 4; ni++)
      bfr[ni] = *(const bf16x8*)&Blds[(wc * 64 + ni * 16 + qq) * 32 + g * 8];
#pragma unroll
    for (int mi = 0; mi < 4; mi++)
#pragma unroll
      for (int ni = 0; ni < 4; ni++)
        acc[mi][ni] = __builtin_amdgcn_mfma_f32_16x16x32_bf16(af[mi], bfr[ni], acc[mi][ni], 0, 0, 0);
  }

  const int colb = nbase + wc * 64;
  const int rowb = mbase + wr * 64;
  if (EPI == 0) {
    unsigned short* Qb = (unsigned short*)out0;
#pragma unroll
    for (int ni = 0; ni < 4; ni++) {
      const int col = colb + ni * 16 + qq;        // 0..2303 ; col = h*192 + d*3 + c
      const float bv = bias[col];
      const int c = col % 3;
      const int dd = (col / 3) & 63;
      const int h = col / 192;
#pragma unroll
      for (int mi = 0; mi < 4; mi++)
#pragma unroll
        for (int r = 0; r < 4; r++) {
          const int row = rowb + mi * 16 + g * 4 + r;   // b*1024 + n
          const int b = row >> 10, n = row & 1023;
          const float v = acc[mi][ni][r] + bv;
          const size_t bh = (size_t)(b * 12 + h);
          if (c == 0)      ((unsigned short*)Qb)[(bh * 1024 + n) * 64 + dd] = f2bf(v * INV_SCALE);
          else if (c == 1) Kb[(bh * 1024 + n) * 64 + dd] = f2bf(v);
          else             VTb[(bh * 64 + dd) * 1024 + n] = f2bf(v);
        }
    }
  } else {
    float* O = (float*)out0;
#pragma unroll
    for (int ni = 0; ni < 4; ni++) {
      const int col = colb + ni * 16 + qq;
      const float bv = bias[col];
#pragma unroll
      for (int mi = 0; mi < 4; mi++)
#pragma unroll
        for (int r = 0; r < 4; r++) {
          const int row = rowb + mi * 16 + g * 4 + r;
          O[(size_t)row * 768 + col] = acc[mi][ni][r] + bv;
        }
    }
  }
}

// Flash attention. Block = 4 waves; each wave owns 16 q-rows (QBLK=64/block), KBLK=64.
// Q pre-scaled by 1/sqrt(768) in GEMM1. K: [bh][n][64], VT: [bh][64][n]. AO: [b*1024+n][768] bf16.
__global__ __launch_bounds__(256) void attn_kernel(
    const unsigned short* __restrict__ Qb,
    const unsigned short* __restrict__ Kb,
    const unsigned short* __restrict__ VTb,
    unsigned short* __restrict__ AO) {
  __shared__ unsigned short Klds[64 * 64];
  __shared__ unsigned short Vlds[64 * 64];
  __shared__ unsigned short Plds[4 * 16 * 64];
  const int tid = threadIdx.x;
  const int w = tid >> 6, lane = tid & 63;
  const int g = lane >> 4, qq = lane & 15;
  const int bh = blockIdx.y;
  const int b = bh / 12, h = bh % 12;
  const int q0 = blockIdx.x * 64 + w * 16;
  const unsigned short* Qh = Qb + (size_t)bh * 65536;
  const unsigned short* Kh = Kb + (size_t)bh * 65536;
  const unsigned short* Vh = VTb + (size_t)bh * 65536;

  bf16x8 qa[2];
#pragma unroll
  for (int kk = 0; kk < 2; kk++)
    qa[kk] = *(const bf16x8*)&Qh[(size_t)(q0 + qq) * 64 + kk * 32 + g * 8];

  float m_run[4], l_run[4];
  f32x4 o[4];
#pragma unroll
  for (int r = 0; r < 4; r++) { m_run[r] = -INFINITY; l_run[r] = 0.f; }
#pragma unroll
  for (int nd = 0; nd < 4; nd++) o[nd] = (f32x4){0.f, 0.f, 0.f, 0.f};

  char* PmyBase = (char*)Plds + w * 2048;   // per-wave private 16x64 bf16

  for (int t0 = 0; t0 < 1024; t0 += 64) {
    __syncthreads();
    // stage K tile [64 tok][64 d] and VT tile [64 d][64 tok], XOR-swizzled 16B chunks
#pragma unroll
    for (int j = 0; j < 2; j++) {
      const int i = tid + j * 256;           // 0..511
      const int row = i >> 3, ch = i & 7;
      const int sw = ch ^ (row & 7);
      uint4 kv = *(const uint4*)&Kh[(size_t)t0 * 64 + i * 8];
      *(uint4*)((char*)Klds + row * 128 + sw * 16) = kv;
      uint4 vv = *(const uint4*)&Vh[(size_t)row * 1024 + t0 + ch * 8];
      *(uint4*)((char*)Vlds + row * 128 + sw * 16) = vv;
    }
    __syncthreads();

    // S = Q K^T (pre-scaled)
    f32x4 s[4];
#pragma unroll
    for (int ni = 0; ni < 4; ni++) s[ni] = (f32x4){0.f, 0.f, 0.f, 0.f};
#pragma unroll
    for (int ni = 0; ni < 4; ni++) {
      const int tok = ni * 16 + qq;
#pragma unroll
      for (int kk = 0; kk < 2; kk++) {
        const int chk = (kk * 4 + g) ^ (tok & 7);
        bf16x8 kbf = *(const bf16x8*)((char*)Klds + tok * 128 + chk * 16);
        s[ni] = __builtin_amdgcn_mfma_f32_16x16x32_bf16(qa[kk], kbf, s[ni], 0, 0, 0);
      }
    }

    // online softmax: row = g*4+r over 16 token-lanes (l&15), x4 ni groups
    float p[4][4];
#pragma unroll
    for (int r = 0; r < 4; r++) {
      float mx = fmaxf(fmaxf(s[0][r], s[1][r]), fmaxf(s[2][r], s[3][r]));
      mx = fmaxf(mx, __shfl_xor(mx, 1));
      mx = fmaxf(mx, __shfl_xor(mx, 2));
      mx = fmaxf(mx, __shfl_xor(mx, 4));
      mx = fmaxf(mx, __shfl_xor(mx, 8));
      const float nm = fmaxf(m_run[r], mx);
      const float corr = exp2f((m_run[r] - nm) * LOG2E);
      float rs = 0.f;
#pragma unroll
      for (int ni = 0; ni < 4; ni++) {
        float e = exp2f((s[ni][r] - nm) * LOG2E);
        p[ni][r] = e; rs += e;
      }
      rs += __shfl_xor(rs, 1);
      rs += __shfl_xor(rs, 2);
      rs += __shfl_xor(rs, 4);
      rs += __shfl_xor(rs, 8);
      l_run[r] = l_run[r] * corr + rs;
      m_run[r] = nm;
#pragma unroll
      for (int nd = 0; nd < 4; nd++) o[nd][r] *= corr;
    }

    // P (C-layout) -> per-wave LDS (swizzled) as bf16
#pragma unroll
    for (int ni = 0; ni < 4; ni++) {
      const int tok = ni * 16 + qq;
#pragma unroll
      for (int r = 0; r < 4; r++) {
        const int prow = g * 4 + r;
        const int chp = (tok >> 3) ^ (prow & 7);
        *(unsigned short*)(PmyBase + prow * 128 + chp * 16 + (tok & 7) * 2) = f2bf(p[ni][r]);
      }
    }
    // no barrier: P region is wave-private, same-wave ds ordering via lgkmcnt

    // O += P V  (A = P from LDS, B = VT rows)
#pragma unroll
    for (int nd = 0; nd < 4; nd++) {
      const int vrow = nd * 16 + qq;
#pragma unroll
      for (int kk = 0; kk < 2; kk++) {
        const int chp = (kk * 4 + g) ^ (qq & 7);
        bf16x8 pa = *(const bf16x8*)(PmyBase + qq * 128 + chp * 16);
        const int chv = (kk * 4 + g) ^ (vrow & 7);
        bf16x8 vb = *(const bf16x8*)((char*)Vlds + vrow * 128 + chv * 16);
        o[nd] = __builtin_amdgcn_mfma_f32_16x16x32_bf16(pa, vb, o[nd], 0, 0, 0);
      }
    }
  }

  const int rowg = b * 1024 + q0 + g * 4;
#pragma unroll
  for (int nd = 0; nd < 4; nd++)
#pragma unroll
    for (int r = 0; r < 4; r++) {
      const float val = o[nd][r] / l_run[r];
      AO[(size_t)(rowg + r) * 768 + h * 64 + nd * 16 + qq] = f2bf(val);
    }
}

extern "C" void kernel_launch(void* const* d_in, const int* in_sizes, int n_in,
                              void* d_out, int out_size, void* d_ws, size_t ws_size,
                              hipStream_t stream) {
  const float* x      = (const float*)d_in[0];
  const float* w_qkv  = (const float*)d_in[1];
  const float* b_qkv  = (const float*)d_in[2];
  const float* w_proj = (const float*)d_in[3];
  const float* b_proj = (const float*)d_in[4];

  char* ws = (char*)d_ws;
  unsigned short* xb     = (unsigned short*)(ws);               // 25165824 B
  unsigned short* Qb     = (unsigned short*)(ws + 25165824);    // 25165824 B
  unsigned short* Kb     = (unsigned short*)(ws + 50331648);    // 25165824 B
  unsigned short* VTb    = (unsigned short*)(ws + 75497472);    // 25165824 B
  unsigned short* wqkvb  = (unsigned short*)(ws + 100663296);   // 3538944 B
  unsigned short* wprojb = (unsigned short*)(ws + 104202240);   // 1179648 B
  unsigned short* AO = xb;  // alias: xb dead after GEMM1

  f2bf_kernel<<<12288, 256, 0, stream>>>(x, xb, 3145728);
  f2bf_kernel<<<1728, 256, 0, stream>>>(w_qkv, wqkvb, 442368);
  f2bf_kernel<<<576, 256, 0, stream>>>(w_proj, wprojb, 147456);

  gemm_bt<0><<<dim3(18, 128), 256, 0, stream>>>(xb, wqkvb, b_qkv, (void*)Qb, Kb, VTb);
  attn_kernel<<<dim3(16, 192), 256, 0, stream>>>(Qb, Kb, VTb, AO);
  gemm_bt<1><<<dim3(6, 128), 256, 0, stream>>>(AO, wprojb, b_proj, d_out, nullptr, nullptr);
}